// Round 1
// baseline (225.066 us; speedup 1.0000x reference)
//
#include <hip/hip_runtime.h>
#include <math.h>

#define NB    16        // batch
#define NC    25        // channels
#define HW    65536     // 256*256
#define CHW   (NC * HW)
#define EPSF  1e-8f
#define BPI   64        // blocks per image
#define TPB   256       // threads per block
#define PPT   4         // pixels per thread (float4)

union F4 { float4 v; float a[4]; };

__device__ __forceinline__ float wave_reduce(float v) {
#pragma unroll
    for (int o = 32; o > 0; o >>= 1) v += __shfl_down(v, o, 64);
    return v;
}

__global__ __launch_bounds__(TPB) void yolo_main(const float* __restrict__ outputs,
                                                 const float* __restrict__ labels,
                                                 float* __restrict__ acc) {
    const int b     = blockIdx.x / BPI;
    const int chunk = blockIdx.x % BPI;
    const int hw0   = chunk * (HW / BPI) + threadIdx.x * PPT;

    const float4* op = (const float4*)(outputs + (size_t)b * CHW + hw0);
    const float4* lp = (const float4*)(labels  + (size_t)b * CHW + hw0);
    const int cs = HW / 4;   // float4 stride between channels

    F4 x, y;
    x.v = op[0];
    y.v = lp[0];

    float obj = 0.f, szs = 0.f, offs = 0.f, cls = 0.f;
    float tp = 0.f, fp = 0.f, fn = 0.f;

    // channel 0: objectness BCE + F1 counts
#pragma unroll
    for (int i = 0; i < 4; ++i) {
        float xv = x.a[i], yv = y.a[i];
        float xc = fminf(fmaxf(xv,        EPSF), 1.0f - EPSF);
        float x1 = fminf(fmaxf(1.0f - xv, EPSF), 1.0f - EPSF);
        obj += -yv * (1.0f - xc) * __logf(xc)
               - (1.0f - yv) * (1.0f - x1) * __logf(x1);
        float p  = (xv > 0.5f) ? 1.f : 0.f;
        float yt = (yv > 0.5f) ? 1.f : 0.f;
        tp += p * yt;
        fp += p * (1.f - yt);
        fn += (1.f - p) * yt;
    }

    // channels 1..2: size L1, 3..4: offset L1 (masked by y)
#pragma unroll
    for (int c = 1; c <= 2; ++c) {
        F4 o, l;
        o.v = op[c * cs];
        l.v = lp[c * cs];
#pragma unroll
        for (int i = 0; i < 4; ++i) szs += y.a[i] * fabsf(o.a[i] - l.a[i]);
    }
#pragma unroll
    for (int c = 3; c <= 4; ++c) {
        F4 o, l;
        o.v = op[c * cs];
        l.v = lp[c * cs];
#pragma unroll
        for (int i = 0; i < 4; ++i) offs += y.a[i] * fabsf(o.a[i] - l.a[i]);
    }

    // channels 5..24: argmax(labels) carrying outputs value; strict > = first-index tie-break
    F4 vmax, vout;
#pragma unroll
    for (int i = 0; i < 4; ++i) { vmax.a[i] = -1.0f; vout.a[i] = 0.0f; }
#pragma unroll
    for (int c = 5; c < NC; ++c) {
        F4 o, l;
        o.v = op[c * cs];
        l.v = lp[c * cs];
#pragma unroll
        for (int i = 0; i < 4; ++i) {
            if (l.a[i] > vmax.a[i]) { vmax.a[i] = l.a[i]; vout.a[i] = o.a[i]; }
        }
    }
#pragma unroll
    for (int i = 0; i < 4; ++i) cls += y.a[i] * (-vout.a[i]);

    // block reduction: 7 values
    obj  = wave_reduce(obj);
    szs  = wave_reduce(szs);
    offs = wave_reduce(offs);
    cls  = wave_reduce(cls);
    tp   = wave_reduce(tp);
    fp   = wave_reduce(fp);
    fn   = wave_reduce(fn);

    __shared__ float sm[TPB / 64][7];
    const int lane = threadIdx.x & 63, wv = threadIdx.x >> 6;
    if (lane == 0) {
        sm[wv][0] = obj;  sm[wv][1] = szs; sm[wv][2] = offs;
        sm[wv][3] = cls;  sm[wv][4] = tp;  sm[wv][5] = fp;  sm[wv][6] = fn;
    }
    __syncthreads();
    if (threadIdx.x < 7) {
        float s = 0.f;
#pragma unroll
        for (int w = 0; w < TPB / 64; ++w) s += sm[w][threadIdx.x];
        if (threadIdx.x < 4) atomicAdd(&acc[threadIdx.x], s);
        else                 atomicAdd(&acc[4 + 3 * b + (threadIdx.x - 4)], s);
    }
}

__global__ void yolo_fin(const float* __restrict__ acc, float* __restrict__ out) {
    if (threadIdx.x == 0) {
        float obj = acc[0];
        float sz  = 0.1f * acc[1];
        float off = 0.1f * acc[2];
        float cls = acc[3];
        float f1 = 0.f;
        for (int b = 0; b < NB; ++b) {
            float tp = acc[4 + 3 * b], fp = acc[5 + 3 * b], fn = acc[6 + 3 * b];
            float den = 2.f * tp + fp + fn;
            f1 += (den > 0.f) ? (2.f * tp) / fmaxf(den, 1.f) : 0.f;
        }
        f1 *= (1.0f / NB);
        out[0] = obj + sz + off + cls;
        out[1] = f1;
        out[2] = obj;
        out[3] = sz;
        out[4] = off;
        out[5] = cls;
    }
}

extern "C" void kernel_launch(void* const* d_in, const int* in_sizes, int n_in,
                              void* d_out, int out_size, void* d_ws, size_t ws_size,
                              hipStream_t stream) {
    const float* outputs = (const float*)d_in[0];
    const float* labels  = (const float*)d_in[1];
    float* acc = (float*)d_ws;   // [0..3]=obj,size,off,cls ; [4+3b..]=tp,fp,fn per image

    hipMemsetAsync(acc, 0, (4 + 3 * NB) * sizeof(float), stream);
    yolo_main<<<NB * BPI, TPB, 0, stream>>>(outputs, labels, acc);
    yolo_fin<<<1, 64, 0, stream>>>(acc, (float*)d_out);
}